// Round 1
// baseline (500.406 us; speedup 1.0000x reference)
//
#include <hip/hip_runtime.h>

typedef unsigned short u16;
typedef __attribute__((ext_vector_type(8))) short short8;
typedef __attribute__((ext_vector_type(4))) float f32x4;

__device__ __forceinline__ u16 f2bf(float f) {
  union { float f; unsigned u; } x; x.f = f;
  unsigned r = (x.u + 0x7fffu + ((x.u >> 16) & 1u)) >> 16;
  return (u16)r;
}

__device__ __forceinline__ f32x4 mfma16(short8 a, short8 b, f32x4 c) {
  return __builtin_amdgcn_mfma_f32_16x16x32_bf16(a, b, c, 0, 0, 0);
}

// in: R x C fp32 row-major  ->  out: C x R bf16 row-major (out[c][r] = in[r][c])
__global__ __launch_bounds__(256) void transpose_cast(const float* __restrict__ in,
                                                      u16* __restrict__ out,
                                                      int R, int C) {
  __shared__ float tile[32][33];
  int c = blockIdx.x * 32 + threadIdx.x;
  int r0 = blockIdx.y * 32;
#pragma unroll
  for (int i = 0; i < 32; i += 8)
    tile[threadIdx.y + i][threadIdx.x] = in[(size_t)(r0 + threadIdx.y + i) * C + c];
  __syncthreads();
  int oc = r0 + threadIdx.x;
  int orow0 = blockIdx.x * 32;
#pragma unroll
  for (int i = 0; i < 32; i += 8)
    out[(size_t)(orow0 + threadIdx.y + i) * R + oc] = f2bf(tile[threadIdx.x][threadIdx.y + i]);
}

// C[m][n] = sum_k A[m][k] * Bt[n][k].  128x128 tile, BK=32, 4 waves (2x2 of 64x64).
// A_F32: A is fp32 (cast to bf16 during staging), else bf16.
// C_F32: C stored fp32, else bf16.
// VT: additionally scatter columns n>=1088 (the V part of qkv) transposed into
//     vt[b][n-1088][t] (b = m/2048, t = m%2048) for the attention PV operand.
template <bool A_F32, bool C_F32, bool VT>
__global__ __launch_bounds__(256) void gemm_bt(const void* __restrict__ Ap,
                                               const u16* __restrict__ Bt,
                                               void* __restrict__ Cp,
                                               u16* __restrict__ vt,
                                               int lda, int ldb, int ldc, int K) {
  __shared__ u16 As[128 * 32];
  __shared__ u16 Bs[128 * 32];
  const int tid = threadIdx.x;
  const int wid = tid >> 6, lane = tid & 63;
  const int quad = lane >> 4, l15 = lane & 15;
  const int m0 = blockIdx.y * 128, n0 = blockIdx.x * 128;
  const int wm = (wid & 1) * 64, wn = (wid >> 1) * 64;
  const int sr = tid >> 2;        // staging row (0..63), +64 on 2nd chunk
  const int sc = (tid & 3) * 8;   // staging col (0,8,16,24)

  f32x4 acc[4][4] = {};

  for (int k0 = 0; k0 < K; k0 += 32) {
    __syncthreads();
#pragma unroll
    for (int cch = 0; cch < 2; ++cch) {
      int row = sr + cch * 64;
      if (A_F32) {
        const float* A = (const float*)Ap;
        const f32x4* src = (const f32x4*)(A + (size_t)(m0 + row) * lda + k0 + sc);
        f32x4 f0 = src[0], f1 = src[1];
        short8 h;
#pragma unroll
        for (int j = 0; j < 4; ++j) { h[j] = (short)f2bf(f0[j]); h[j + 4] = (short)f2bf(f1[j]); }
        *(short8*)&As[row * 32 + sc] = h;
      } else {
        const u16* A = (const u16*)Ap;
        *(short8*)&As[row * 32 + sc] = *(const short8*)(A + (size_t)(m0 + row) * lda + k0 + sc);
      }
      *(short8*)&Bs[row * 32 + sc] = *(const short8*)(Bt + (size_t)(n0 + row) * ldb + k0 + sc);
    }
    __syncthreads();
    short8 a[4], b[4];
#pragma unroll
    for (int i = 0; i < 4; ++i) a[i] = *(const short8*)&As[(wm + 16 * i + l15) * 32 + quad * 8];
#pragma unroll
    for (int j = 0; j < 4; ++j) b[j] = *(const short8*)&Bs[(wn + 16 * j + l15) * 32 + quad * 8];
#pragma unroll
    for (int i = 0; i < 4; ++i)
#pragma unroll
      for (int j = 0; j < 4; ++j)
        acc[i][j] = mfma16(a[i], b[j], acc[i][j]);
  }

#pragma unroll
  for (int i = 0; i < 4; ++i) {
#pragma unroll
    for (int j = 0; j < 4; ++j) {
      const int mrow = m0 + wm + 16 * i + quad * 4;
      const int ncol = n0 + wn + 16 * j + l15;
#pragma unroll
      for (int r = 0; r < 4; ++r) {
        float v = acc[i][j][r];
        if (C_F32) {
          ((float*)Cp)[(size_t)(mrow + r) * ldc + ncol] = v;
        } else {
          u16 hv = f2bf(v);
          ((u16*)Cp)[(size_t)(mrow + r) * ldc + ncol] = hv;
          if (VT) {
            if (ncol >= 1088) {
              int mg = mrow + r;
              int bb = mg >> 11, tt = mg & 2047;
              vt[(size_t)(bb * 64 + (ncol - 1088)) * 2048 + tt] = hv;
            }
          }
        }
      }
    }
  }
}

// Flash causal MQA. grid = 1024: qt = bid&15 (q-tile of 128), bh = bid>>4, b=bh>>4, h=bh&15.
// 4 waves, 32 q-rows each. KT=64. Q/K from qkv (d-contiguous), V^T from vt (kv-contiguous).
__global__ __launch_bounds__(256) void attn_kernel(const u16* __restrict__ qkv,
                                                   const u16* __restrict__ vt,
                                                   u16* __restrict__ y) {
  const int T = 2048, LD = 1152;
  __shared__ u16 Qs[128 * 64];
  __shared__ u16 Ks[64 * 64];
  __shared__ u16 Vts[64 * 64];
  __shared__ u16 Ps[4][32 * 72];  // per-wave P, row stride 72 (16B-aligned, softens conflicts)

  const int bid = blockIdx.x;
  const int qt = bid & 15, bh = bid >> 4;
  const int b = bh >> 4, h = bh & 15;
  const int q0 = qt * 128;
  const int tid = threadIdx.x, wid = tid >> 6, lane = tid & 63;
  const int quad = lane >> 4, l15 = lane & 15;
  const int wq = wid * 32;
  const u16* qkvb = qkv + (size_t)b * T * LD;
  const u16* vtb = vt + (size_t)b * 64 * 2048;

#pragma unroll
  for (int c = 0; c < 4; ++c) {
    int e = tid * 8 + c * 2048;
    int row = e >> 6, col = e & 63;
    *(short8*)&Qs[row * 64 + col] = *(const short8*)(qkvb + (size_t)(q0 + row) * LD + h * 64 + col);
  }

  f32x4 acc_o[2][4] = {};
  float m_st[2][4], l_st[2][4];
#pragma unroll
  for (int i = 0; i < 2; ++i)
#pragma unroll
    for (int r = 0; r < 4; ++r) { m_st[i][r] = -1e30f; l_st[i][r] = 0.f; }

  const int ktmax = 2 * qt + 2;
  for (int kt = 0; kt < ktmax; ++kt) {
    const int kv0 = kt * 64;
    __syncthreads();
#pragma unroll
    for (int c = 0; c < 2; ++c) {
      int e = tid * 8 + c * 2048;
      int row = e >> 6, col = e & 63;
      *(short8*)&Ks[row * 64 + col] = *(const short8*)(qkvb + (size_t)(kv0 + row) * LD + 1024 + col);
      *(short8*)&Vts[row * 64 + col] = *(const short8*)(vtb + (size_t)row * 2048 + kv0 + col);
    }
    __syncthreads();

    // S = Q K^T for this wave's 32 q-rows
    f32x4 s[2][4] = {};
#pragma unroll
    for (int ks = 0; ks < 2; ++ks) {
      short8 aq[2], bk[4];
#pragma unroll
      for (int i = 0; i < 2; ++i) aq[i] = *(const short8*)&Qs[(wq + 16 * i + l15) * 64 + ks * 32 + quad * 8];
#pragma unroll
      for (int j = 0; j < 4; ++j) bk[j] = *(const short8*)&Ks[(16 * j + l15) * 64 + ks * 32 + quad * 8];
#pragma unroll
      for (int i = 0; i < 2; ++i)
#pragma unroll
        for (int j = 0; j < 4; ++j)
          s[i][j] = mfma16(aq[i], bk[j], s[i][j]);
    }

    const bool needMask = (kv0 + 63 > q0 + wq);
#pragma unroll
    for (int i = 0; i < 2; ++i) {
#pragma unroll
      for (int r = 0; r < 4; ++r) {
        const int qrow = q0 + wq + 16 * i + quad * 4 + r;
        float sv[4];
#pragma unroll
        for (int j = 0; j < 4; ++j) {
          float xv = s[i][j][r] * 0.125f;
          if (needMask && (kv0 + 16 * j + l15 > qrow)) xv = -1e30f;
          sv[j] = xv;
        }
        float mx = fmaxf(fmaxf(sv[0], sv[1]), fmaxf(sv[2], sv[3]));
#pragma unroll
        for (int d = 1; d <= 8; d <<= 1) mx = fmaxf(mx, __shfl_xor(mx, d));
        const float mnew = fmaxf(m_st[i][r], mx);
        const float alpha = exp2f((m_st[i][r] - mnew) * 1.44269504f);
        float pp[4];
        float rsum = 0.f;
#pragma unroll
        for (int j = 0; j < 4; ++j) { pp[j] = exp2f((sv[j] - mnew) * 1.44269504f); rsum += pp[j]; }
#pragma unroll
        for (int d = 1; d <= 8; d <<= 1) rsum += __shfl_xor(rsum, d);
        m_st[i][r] = mnew;
        l_st[i][r] = l_st[i][r] * alpha + rsum;
#pragma unroll
        for (int n = 0; n < 4; ++n) acc_o[i][n][r] *= alpha;
        const int prow = 16 * i + quad * 4 + r;
#pragma unroll
        for (int j = 0; j < 4; ++j) Ps[wid][prow * 72 + 16 * j + l15] = f2bf(pp[j]);
      }
    }
    __syncthreads();  // P visibility (and keeps Ks/Vts stable until here)

    // O += P V
#pragma unroll
    for (int ks = 0; ks < 2; ++ks) {
      short8 ap[2], bv[4];
#pragma unroll
      for (int i = 0; i < 2; ++i) ap[i] = *(const short8*)&Ps[wid][(16 * i + l15) * 72 + ks * 32 + quad * 8];
#pragma unroll
      for (int n = 0; n < 4; ++n) bv[n] = *(const short8*)&Vts[(16 * n + l15) * 64 + ks * 32 + quad * 8];
#pragma unroll
      for (int i = 0; i < 2; ++i)
#pragma unroll
        for (int n = 0; n < 4; ++n)
          acc_o[i][n] = mfma16(ap[i], bv[n], acc_o[i][n]);
    }
  }

#pragma unroll
  for (int i = 0; i < 2; ++i) {
#pragma unroll
    for (int r = 0; r < 4; ++r) {
      const float inv = 1.f / l_st[i][r];
      const int qrow = q0 + wq + 16 * i + quad * 4 + r;
#pragma unroll
      for (int n = 0; n < 4; ++n)
        y[(size_t)(b * T + qrow) * 1024 + h * 64 + 16 * n + l15] = f2bf(acc_o[i][n][r] * inv);
    }
  }
}

extern "C" void kernel_launch(void* const* d_in, const int* in_sizes, int n_in,
                              void* d_out, int out_size, void* d_ws, size_t ws_size,
                              hipStream_t stream) {
  const float* x = (const float*)d_in[0];       // (4,2048,1024)
  const float* w_attn = (const float*)d_in[1];  // (1024,1152)
  const float* w_proj = (const float*)d_in[2];  // (1024,1024)
  float* out = (float*)d_out;                   // (4,2048,1024) fp32
  char* ws = (char*)d_ws;

  u16* wat = (u16*)ws;                                            // 1152x1024 bf16 (w_attn^T)
  u16* wpt = (u16*)(ws + 2359296);                                // 1024x1024 bf16 (w_proj^T)
  u16* qkv = (u16*)(ws + 2359296 + 2097152);                      // 8192x1152 bf16
  u16* vt  = (u16*)(ws + 2359296 + 2097152 + 18874368);           // 4x64x2048 bf16 (V^T per batch)
  u16* y   = (u16*)(ws + 2359296 + 2097152 + 18874368 + 1048576); // 8192x1024 bf16

  transpose_cast<<<dim3(36, 32), dim3(32, 8), 0, stream>>>(w_attn, wat, 1024, 1152);
  transpose_cast<<<dim3(32, 32), dim3(32, 8), 0, stream>>>(w_proj, wpt, 1024, 1024);
  gemm_bt<true, false, true><<<dim3(9, 64), 256, 0, stream>>>(x, wat, qkv, vt, 1024, 1024, 1152, 1024);
  attn_kernel<<<dim3(1024), dim3(256), 0, stream>>>(qkv, vt, y);
  gemm_bt<false, true, false><<<dim3(8, 64), 256, 0, stream>>>(y, wpt, out, nullptr, 1024, 1024, 1024, 1024);
}

// Round 2
// 261.427 us; speedup vs baseline: 1.9141x; 1.9141x over previous
//
#include <hip/hip_runtime.h>

typedef unsigned short u16;
typedef unsigned int u32;
typedef __attribute__((ext_vector_type(8))) short short8;
typedef __attribute__((ext_vector_type(4))) float f32x4;
typedef __attribute__((ext_vector_type(4))) u16 u16x4;

__device__ __forceinline__ u16 f2bf(float f) {
  union { float f; unsigned u; } x; x.f = f;
  unsigned r = (x.u + 0x7fffu + ((x.u >> 16) & 1u)) >> 16;
  return (u16)r;
}

__device__ __forceinline__ u32 pack2bf(float a, float b) {
  return (u32)f2bf(a) | ((u32)f2bf(b) << 16);
}

__device__ __forceinline__ f32x4 mfma16(short8 a, short8 b, f32x4 c) {
  return __builtin_amdgcn_mfma_f32_16x16x32_bf16(a, b, c, 0, 0, 0);
}

// async global->LDS, 16B per lane. LDS dest = wave-uniform base + lane*16.
__device__ __forceinline__ void gload16(const u16* g, u16* l) {
  __builtin_amdgcn_global_load_lds((const __attribute__((address_space(1))) void*)g,
                                   (__attribute__((address_space(3))) void*)l, 16, 0, 0);
}

// in: R x C fp32 row-major  ->  out: C x R bf16 row-major
__global__ __launch_bounds__(256) void transpose_cast(const float* __restrict__ in,
                                                      u16* __restrict__ out,
                                                      int R, int C) {
  __shared__ float tile[32][33];
  int c = blockIdx.x * 32 + threadIdx.x;
  int r0 = blockIdx.y * 32;
#pragma unroll
  for (int i = 0; i < 32; i += 8)
    tile[threadIdx.y + i][threadIdx.x] = in[(size_t)(r0 + threadIdx.y + i) * C + c];
  __syncthreads();
  int oc = r0 + threadIdx.x;
  int orow0 = blockIdx.x * 32;
#pragma unroll
  for (int i = 0; i < 32; i += 8)
    out[(size_t)(orow0 + threadIdx.y + i) * R + oc] = f2bf(tile[threadIdx.x][threadIdx.y + i]);
}

// C[m][n] = sum_k A[m][k] * Bt[n][k].  128x128 tile, BK=32, 4 waves.
template <bool A_F32, bool C_F32, bool VT>
__global__ __launch_bounds__(256) void gemm_bt(const void* __restrict__ Ap,
                                               const u16* __restrict__ Bt,
                                               void* __restrict__ Cp,
                                               u16* __restrict__ vt,
                                               int lda, int ldb, int ldc, int K) {
  __shared__ u16 As[128 * 32];
  __shared__ u16 Bs[128 * 32];
  const int tid = threadIdx.x;
  const int wid = tid >> 6, lane = tid & 63;
  const int quad = lane >> 4, l15 = lane & 15;
  const int m0 = blockIdx.y * 128, n0 = blockIdx.x * 128;
  const int wm = (wid & 1) * 64, wn = (wid >> 1) * 64;
  const int sr = tid >> 2;        // staging row (0..63)
  const int sc = (tid & 3) * 8;   // staging col in u16

  f32x4 acc[4][4] = {};

  for (int k0 = 0; k0 < K; k0 += 32) {
    __syncthreads();
#pragma unroll
    for (int cch = 0; cch < 2; ++cch) {
      int row = sr + cch * 64;
      if (A_F32) {
        const float* A = (const float*)Ap;
        const f32x4* src = (const f32x4*)(A + (size_t)(m0 + row) * lda + k0 + sc);
        f32x4 f0 = src[0], f1 = src[1];
        short8 h;
#pragma unroll
        for (int j = 0; j < 4; ++j) { h[j] = (short)f2bf(f0[j]); h[j + 4] = (short)f2bf(f1[j]); }
        *(short8*)&As[row * 32 + sc] = h;
      } else {
        const u16* A = (const u16*)Ap;
        gload16(A + (size_t)(m0 + row) * lda + k0 + sc, &As[wid * 512 + cch * 2048]);
      }
      gload16(Bt + (size_t)(n0 + row) * ldb + k0 + sc, &Bs[wid * 512 + cch * 2048]);
    }
    __syncthreads();
    short8 a[4], b[4];
#pragma unroll
    for (int i = 0; i < 4; ++i) a[i] = *(const short8*)&As[(wm + 16 * i + l15) * 32 + quad * 8];
#pragma unroll
    for (int j = 0; j < 4; ++j) b[j] = *(const short8*)&Bs[(wn + 16 * j + l15) * 32 + quad * 8];
#pragma unroll
    for (int i = 0; i < 4; ++i)
#pragma unroll
      for (int j = 0; j < 4; ++j)
        acc[i][j] = mfma16(a[i], b[j], acc[i][j]);
  }

#pragma unroll
  for (int i = 0; i < 4; ++i) {
#pragma unroll
    for (int j = 0; j < 4; ++j) {
      const int mrow = m0 + wm + 16 * i + quad * 4;
      const int ncol = n0 + wn + 16 * j + l15;
#pragma unroll
      for (int r = 0; r < 4; ++r) {
        float v = acc[i][j][r];
        if (C_F32) {
          ((float*)Cp)[(size_t)(mrow + r) * ldc + ncol] = v;
        } else {
          u16 hv = f2bf(v);
          ((u16*)Cp)[(size_t)(mrow + r) * ldc + ncol] = hv;
          if (VT) {
            if (ncol >= 1088) {
              int mg = mrow + r;
              int bb = mg >> 11, tt = mg & 2047;
              vt[(size_t)(bb * 64 + (ncol - 1088)) * 2048 + tt] = hv;
            }
          }
        }
      }
    }
  }
}

// Flash causal MQA, S^T formulation, paired q-tiles for load balance.
// grid = 512: pr = bid&7, bh = bid>>3, b = bh>>4, h = bh&15.
// Each block: phase 0 -> qt = 15-pr, phase 1 -> qt = pr  (34 k-tiles total, uniform).
// 4 waves x 32 q-rows. Q in registers. K/V staged in LDS with stride-72 padding.
__global__ __launch_bounds__(256) void attn_kernel(const u16* __restrict__ qkv,
                                                   const u16* __restrict__ vt,
                                                   u16* __restrict__ y) {
  const int T = 2048, LD = 1152;
  __shared__ u16 Ks[64 * 72];   // [kv][d], padded
  __shared__ u16 Vts[64 * 72];  // [d][kv], padded
  __shared__ u16 Pw[4][2][16 * 72];  // per-wave, per-jt: [q 16][kv 64+pad]

  const int bid = blockIdx.x;
  const int pr = bid & 7, bh = bid >> 3;
  const int b = bh >> 4, h = bh & 15;
  const int tid = threadIdx.x, wid = tid >> 6, lane = tid & 63;
  const int quad = lane >> 4, l15 = lane & 15;
  const int wq = wid * 32;
  const u16* qkvb = qkv + (size_t)b * T * LD;
  const u16* vtb = vt + (size_t)b * 64 * 2048;

  // staging thread->tile mapping (two 4KB chunks of the 64x64 tile)
  const int sr0 = (tid * 8) >> 6, sc0 = (tid * 8) & 63;
  const int sr1 = (tid * 8 + 2048) >> 6, sc1 = (tid * 8 + 2048) & 63;

#pragma unroll
  for (int ph = 0; ph < 2; ++ph) {
    const int qt = ph ? pr : (15 - pr);
    const int q0 = qt * 128;
    const int ktmax = 2 * qt + 2;

    short8 qreg[2][2];
#pragma unroll
    for (int jt = 0; jt < 2; ++jt)
#pragma unroll
      for (int ks = 0; ks < 2; ++ks)
        qreg[jt][ks] = *(const short8*)(qkvb + (size_t)(q0 + wq + 16 * jt + l15) * LD + h * 64 + ks * 32 + quad * 8);

    f32x4 acc[4][2] = {};
    float m_s[2] = {-1e30f, -1e30f}, l_s[2] = {0.f, 0.f};

    // prefetch k-tile 0
    short8 kr0 = *(const short8*)(qkvb + (size_t)sr0 * LD + 1024 + sc0);
    short8 kr1 = *(const short8*)(qkvb + (size_t)sr1 * LD + 1024 + sc1);
    short8 vr0 = *(const short8*)(vtb + (size_t)sr0 * 2048 + sc0);
    short8 vr1 = *(const short8*)(vtb + (size_t)sr1 * 2048 + sc1);

    for (int kt = 0; kt < ktmax; ++kt) {
      const int kv0 = kt * 64;
      __syncthreads();
      *(short8*)&Ks[sr0 * 72 + sc0] = kr0;
      *(short8*)&Ks[sr1 * 72 + sc1] = kr1;
      *(short8*)&Vts[sr0 * 72 + sc0] = vr0;
      *(short8*)&Vts[sr1 * 72 + sc1] = vr1;
      __syncthreads();
      if (kt + 1 < ktmax) {
        const int nv0 = kv0 + 64;
        kr0 = *(const short8*)(qkvb + (size_t)(nv0 + sr0) * LD + 1024 + sc0);
        kr1 = *(const short8*)(qkvb + (size_t)(nv0 + sr1) * LD + 1024 + sc1);
        vr0 = *(const short8*)(vtb + (size_t)sr0 * 2048 + nv0 + sc0);
        vr1 = *(const short8*)(vtb + (size_t)sr1 * 2048 + nv0 + sc1);
      }
      if (kv0 > q0 + wq + 31) continue;  // fully masked for this wave (barriers already done)

      // S^T = K * Q^T : rows kv, cols q
      f32x4 st[4][2] = {};
#pragma unroll
      for (int ks = 0; ks < 2; ++ks) {
        short8 kf[4];
#pragma unroll
        for (int i = 0; i < 4; ++i) kf[i] = *(const short8*)&Ks[(16 * i + l15) * 72 + ks * 32 + quad * 8];
#pragma unroll
        for (int i = 0; i < 4; ++i)
#pragma unroll
          for (int jt = 0; jt < 2; ++jt)
            st[i][jt] = mfma16(kf[i], qreg[jt][ks], st[i][jt]);
      }

      const bool needMask = (kv0 + 63 > q0 + wq);
#pragma unroll
      for (int jt = 0; jt < 2; ++jt) {
        const int qg = q0 + wq + 16 * jt + l15;
        float sv[4][4];
#pragma unroll
        for (int i = 0; i < 4; ++i)
#pragma unroll
          for (int r = 0; r < 4; ++r) {
            float xv = st[i][jt][r] * 0.125f;
            if (needMask && (kv0 + 16 * i + quad * 4 + r > qg)) xv = -1e30f;
            sv[i][r] = xv;
          }
        float mx = sv[0][0];
#pragma unroll
        for (int i = 0; i < 4; ++i)
#pragma unroll
          for (int r = 0; r < 4; ++r) mx = fmaxf(mx, sv[i][r]);
        mx = fmaxf(mx, __shfl_xor(mx, 16));
        mx = fmaxf(mx, __shfl_xor(mx, 32));
        const float mnew = fmaxf(m_s[jt], mx);
        const float alpha = __builtin_amdgcn_exp2f((m_s[jt] - mnew) * 1.44269504f);
        float pp[4][4], rs = 0.f;
#pragma unroll
        for (int i = 0; i < 4; ++i)
#pragma unroll
          for (int r = 0; r < 4; ++r) {
            pp[i][r] = __builtin_amdgcn_exp2f((sv[i][r] - mnew) * 1.44269504f);
            rs += pp[i][r];
          }
        rs += __shfl_xor(rs, 16);
        rs += __shfl_xor(rs, 32);
        m_s[jt] = mnew;
        l_s[jt] = l_s[jt] * alpha + rs;
#pragma unroll
        for (int id = 0; id < 4; ++id)
#pragma unroll
          for (int r = 0; r < 4; ++r) acc[id][jt][r] *= alpha;

        // P^T (C-layout) -> per-wave LDS, packed u32 writes
        u16* pw = &Pw[wid][jt][0];
#pragma unroll
        for (int i = 0; i < 4; ++i)
#pragma unroll
          for (int p = 0; p < 2; ++p)
            *(u32*)&pw[l15 * 72 + 16 * i + quad * 4 + 2 * p] = pack2bf(pp[i][2 * p], pp[i][2 * p + 1]);

        // O^T += V^T * P^T   (wave-local LDS round-trip, no barrier)
#pragma unroll
        for (int ks = 0; ks < 2; ++ks) {
          short8 pf = *(const short8*)&pw[l15 * 72 + ks * 32 + quad * 8];
#pragma unroll
          for (int id = 0; id < 4; ++id) {
            short8 vf = *(const short8*)&Vts[(16 * id + l15) * 72 + ks * 32 + quad * 8];
            acc[id][jt] = mfma16(vf, pf, acc[id][jt]);
          }
        }
      }
    }

    // epilogue: O^T rows d (register axis) -> 8B vectorized stores
#pragma unroll
    for (int jt = 0; jt < 2; ++jt) {
      const float inv = 1.f / l_s[jt];
      const int qg = q0 + wq + 16 * jt + l15;
#pragma unroll
      for (int id = 0; id < 4; ++id) {
        u16x4 o;
#pragma unroll
        for (int r = 0; r < 4; ++r) o[r] = f2bf(acc[id][jt][r] * inv);
        *(u16x4*)(y + (size_t)(b * T + qg) * 1024 + h * 64 + 16 * id + quad * 4) = o;
      }
    }
  }
}

extern "C" void kernel_launch(void* const* d_in, const int* in_sizes, int n_in,
                              void* d_out, int out_size, void* d_ws, size_t ws_size,
                              hipStream_t stream) {
  const float* x = (const float*)d_in[0];       // (4,2048,1024)
  const float* w_attn = (const float*)d_in[1];  // (1024,1152)
  const float* w_proj = (const float*)d_in[2];  // (1024,1024)
  float* out = (float*)d_out;                   // (4,2048,1024) fp32
  char* ws = (char*)d_ws;

  u16* wat = (u16*)ws;                                            // 1152x1024 bf16
  u16* wpt = (u16*)(ws + 2359296);                                // 1024x1024 bf16
  u16* qkv = (u16*)(ws + 2359296 + 2097152);                      // 8192x1152 bf16
  u16* vt  = (u16*)(ws + 2359296 + 2097152 + 18874368);           // 4x64x2048 bf16
  u16* y   = (u16*)(ws + 2359296 + 2097152 + 18874368 + 1048576); // 8192x1024 bf16

  transpose_cast<<<dim3(36, 32), dim3(32, 8), 0, stream>>>(w_attn, wat, 1024, 1152);
  transpose_cast<<<dim3(32, 32), dim3(32, 8), 0, stream>>>(w_proj, wpt, 1024, 1024);
  gemm_bt<true, false, true><<<dim3(9, 64), 256, 0, stream>>>(x, wat, qkv, vt, 1024, 1024, 1152, 1024);
  attn_kernel<<<dim3(512), dim3(256), 0, stream>>>(qkv, vt, y);
  gemm_bt<false, true, false><<<dim3(8, 64), 256, 0, stream>>>(y, wpt, out, nullptr, 1024, 1024, 1024, 1024);
}